// Round 13
// baseline (80.533 us; speedup 1.0000x reference)
//
#include <hip/hip_runtime.h>

typedef unsigned short u16;
typedef float f32x4 __attribute__((ext_vector_type(4)));
typedef short bf16x8 __attribute__((ext_vector_type(8)));

constexpr int Bn = 4, Ln = 512, Mn = 32, EMBn = 512, Hn = 8, HSn = 64;
constexpr int Rn = Mn * Hn; // 256
constexpr unsigned MAGIC = 0x5EEDF00Du;

__device__ __forceinline__ float wave_sum(float v) {
#pragma unroll
  for (int off = 1; off < 64; off <<= 1) v += __shfl_xor(v, off, 64);
  return v;
}
__device__ __forceinline__ u16 f2bf(float f) {
  unsigned u = __float_as_uint(f);
  unsigned r = (u + 0x7FFFu + ((u >> 16) & 1u)) >> 16;
  return (u16)r;
}
__device__ __forceinline__ unsigned pack2(float a, float b) {
  return (unsigned)f2bf(a) | ((unsigned)f2bf(b) << 16);
}
__device__ __forceinline__ float bf2f(unsigned us) {
  return __uint_as_float(us << 16);
}

// ---------------------------------------------------------------------------
// K1: blocks [0,128): P = cells*q_w via 32x32 MFMA (K=64), + pb (et==0).
//     blocks [128,640): LayerNorm -> h_bf16.   (R12 verbatim)
// ---------------------------------------------------------------------------
__global__ __launch_bounds__(256) void ln_pproj_kernel(
    const float* __restrict__ x, const float* __restrict__ gam,
    const float* __restrict__ bet, const float* __restrict__ cells,
    const float* __restrict__ q_w, const float* __restrict__ q_b,
    u16* __restrict__ hb, u16* __restrict__ Pb, float* __restrict__ pb) {
  __shared__ __align__(16) char PSM[8192];
  int bid = blockIdx.x, tid = threadIdx.x;
  if (bid < 128) {
    int hh = bid >> 4, et = bid & 15;
    int e0 = et * 32;
    const int lane = tid & 63;
    {
      int row = tid >> 3, sc8 = (tid & 7) * 8;
      const float* src = cells + (size_t)(row * Hn + hh) * HSn + sc8;
      float4 c0 = *(const float4*)src;
      float4 c1 = *(const float4*)(src + 4);
      uint4 st;
      st.x = pack2(c0.x, c0.y);
      st.y = pack2(c0.z, c0.w);
      st.z = pack2(c1.x, c1.y);
      st.w = pack2(c1.z, c1.w);
      *(uint4*)(PSM + row * 128 + (((unsigned)(sc8 * 2)) ^ ((row & 7) << 4))) =
          st;
    }
    {
      int srow = tid >> 2, eq = (tid & 3) * 8;
      const float* src = q_w + (size_t)(hh * HSn + srow) * EMBn + e0 + eq;
      float4 q0 = *(const float4*)src;
      float4 q1 = *(const float4*)(src + 4);
      u16 qv[8];
      qv[0] = f2bf(q0.x); qv[1] = f2bf(q0.y);
      qv[2] = f2bf(q0.z); qv[3] = f2bf(q0.w);
      qv[4] = f2bf(q1.x); qv[5] = f2bf(q1.y);
      qv[6] = f2bf(q1.z); qv[7] = f2bf(q1.w);
#pragma unroll
      for (int k = 0; k < 8; ++k) {
        int e = eq + k;
        unsigned swz =
            (((unsigned)(e & 7)) << 4) ^ (((unsigned)((e >> 3) & 3)) << 5);
        *(u16*)(PSM + 4096 + e * 128 + (((unsigned)(srow * 2)) ^ swz)) = qv[k];
      }
    }
    __syncthreads();
    const int wave = tid >> 6;
    const int wr = wave >> 1, wc = wave & 1;
    const int n = lane & 15;
    const int ra = wr * 16 + n;
    const int eb = wc * 16 + n;
    const unsigned asw = (unsigned)((ra & 7) << 4);
    const unsigned bsw =
        (((unsigned)(eb & 7)) << 4) ^ (((unsigned)((eb >> 3) & 3)) << 5);
    const unsigned kg = (unsigned)((lane >> 4) * 16);
    f32x4 acc = {0.f, 0.f, 0.f, 0.f};
#pragma unroll
    for (int kk = 0; kk < 2; ++kk) {
      unsigned kb = kk * 64 + kg;
      bf16x8 a = *(const bf16x8*)(PSM + ra * 128 + (kb ^ asw));
      bf16x8 bv = *(const bf16x8*)(PSM + 4096 + eb * 128 + (kb ^ bsw));
      acc = __builtin_amdgcn_mfma_f32_16x16x32_bf16(a, bv, acc, 0, 0, 0);
    }
    const int m0 = wr * 16 + ((lane >> 4) << 2);
    const int eg = e0 + wc * 16 + n;
#pragma unroll
    for (int j = 0; j < 4; ++j) {
      Pb[(size_t)((m0 + j) * Hn + hh) * EMBn + eg] = f2bf(acc[j]);
    }
    if (et == 0) {
      int m = tid >> 3, sg = tid & 7;
      const float* cp = cells + (size_t)(m * Hn + hh) * HSn + sg * 8;
      const float* qp = q_b + hh * HSn + sg * 8;
      float p = 0.f;
#pragma unroll
      for (int k = 0; k < 8; ++k) p += cp[k] * qp[k];
      p += __shfl_xor(p, 1, 64);
      p += __shfl_xor(p, 2, 64);
      p += __shfl_xor(p, 4, 64);
      if (sg == 0) pb[m * Hn + hh] = p;
    }
  } else {
    int row = (bid - 128) * 4 + (tid >> 6), lane = tid & 63;
    const float* xr = x + (size_t)row * EMBn + lane * 8;
    float4 a0 = *(const float4*)xr;
    float4 a1 = *(const float4*)(xr + 4);
    float s = a0.x + a0.y + a0.z + a0.w + a1.x + a1.y + a1.z + a1.w;
    float ss = a0.x * a0.x + a0.y * a0.y + a0.z * a0.z + a0.w * a0.w +
               a1.x * a1.x + a1.y * a1.y + a1.z * a1.z + a1.w * a1.w;
    s = wave_sum(s);
    ss = wave_sum(ss);
    float mu = s * (1.0f / EMBn);
    float var = ss * (1.0f / EMBn) - mu * mu;
    float rstd = rsqrtf(var + 1e-5f);
    const float* gp = gam + lane * 8;
    const float* bp = bet + lane * 8;
    float4 g0 = *(const float4*)gp, g1 = *(const float4*)(gp + 4);
    float4 b0 = *(const float4*)bp, b1 = *(const float4*)(bp + 4);
    float4 o0, o1;
    o0.x = (a0.x - mu) * rstd * g0.x + b0.x;
    o0.y = (a0.y - mu) * rstd * g0.y + b0.y;
    o0.z = (a0.z - mu) * rstd * g0.z + b0.z;
    o0.w = (a0.w - mu) * rstd * g0.w + b0.w;
    o1.x = (a1.x - mu) * rstd * g1.x + b1.x;
    o1.y = (a1.y - mu) * rstd * g1.y + b1.y;
    o1.z = (a1.z - mu) * rstd * g1.z + b1.z;
    o1.w = (a1.w - mu) * rstd * g1.w + b1.w;
    uint4 st;
    st.x = pack2(o0.x, o0.y);
    st.y = pack2(o0.z, o0.w);
    st.z = pack2(o1.x, o1.y);
    st.w = pack2(o1.z, o1.w);
    *(uint4*)&hb[(size_t)row * EMBn + lane * 8] = st;
  }
}

// ---------------------------------------------------------------------------
// K2: merged escore + transpose + gmat with per-tile readiness flags.
// blocks [0,512): E-tiles (producers). [512,768): h-transpose (producers).
// [768,1280): gmat tiles (consumers; wait on 16 eflags + 8 tflags).
// All 1280 blocks co-resident (8 blocks/CU capacity) -> no deadlock.
// ---------------------------------------------------------------------------
__global__ __launch_bounds__(256) void mid_kernel(
    const u16* __restrict__ hb, const u16* __restrict__ Pb,
    const float* __restrict__ pb, u16* __restrict__ Eb,
    float* __restrict__ spart, u16* __restrict__ htb, u16* __restrict__ Gb,
    unsigned* __restrict__ flg) {
  __shared__ u16 smem[8192];
  __shared__ float sInvS[32];
  unsigned* eflag = flg;              // [b][rt 8][lt 16], stride 16 u32 (64B)
  unsigned* tflag = flg + 512 * 16;   // [b][lt 8][jt 8], stride 16 u32
  int bid = blockIdx.x, tid = threadIdx.x;

  if (bid < 512) {
    // ---------------- escore producer (R12 verbatim body)
    int b = bid >> 7, rem = bid & 127;
    int r0 = (rem >> 4) * 32, l0 = (rem & 15) * 32;
    const u16* Ag = Pb;
    const u16* Bg = hb + (size_t)b * Ln * EMBn;
    u16* Cg = Eb + (size_t)b * Rn * Ln;
    float* sp = spart + (size_t)b * Rn * 32;

    const int wave = tid >> 6, lane = tid & 63;
    const int srow = tid >> 3, sblk = tid & 7;
    const u16* gsrcA = Ag + (size_t)(r0 + srow) * 512 + sblk * 8;
    const u16* gsrcB = Bg + (size_t)(l0 + srow) * 512 + sblk * 8;
    const unsigned lswz = (unsigned)(((sblk * 16) ^ ((srow & 7) << 4)) >> 1);
    const unsigned lofsA = (unsigned)(srow * 64) + lswz;
    const unsigned lofsB = 4096u + (unsigned)(srow * 64) + lswz;

    uint4 rvA = *(const uint4*)gsrcA;
    uint4 rvB = *(const uint4*)gsrcB;
    *(uint4*)&smem[lofsA] = rvA;
    *(uint4*)&smem[lofsB] = rvB;
    __syncthreads();

    f32x4 acc = {0.f, 0.f, 0.f, 0.f};
    const int wr = wave >> 1, wc = wave & 1;
    const int ra = wr * 16 + (lane & 15);
    const int nb = wc * 16 + (lane & 15);
    const unsigned asw = (unsigned)((ra & 7) << 4);
    const unsigned bsw = (unsigned)((nb & 7) << 4);
    const unsigned kg = (unsigned)((lane >> 4) * 16);

#pragma unroll
    for (int c = 0; c < 8; ++c) {
      const int cur = c & 1;
      if (c < 7) {
        rvA = *(const uint4*)(gsrcA + (c + 1) * 64);
        rvB = *(const uint4*)(gsrcB + (c + 1) * 64);
      }
      const char* Ab = (const char*)(smem + cur * 2048);
      const char* Bb = (const char*)(smem + 4096 + cur * 2048);
#pragma unroll
      for (int ks = 0; ks < 2; ++ks) {
        unsigned kb = ks * 64 + kg;
        bf16x8 a = *(const bf16x8*)(Ab + ra * 128 + (kb ^ asw));
        bf16x8 b0 = *(const bf16x8*)(Bb + nb * 128 + (kb ^ bsw));
        acc = __builtin_amdgcn_mfma_f32_16x16x32_bf16(a, b0, acc, 0, 0, 0);
      }
      if (c < 7) {
        unsigned bo = (unsigned)((cur ^ 1) * 2048);
        *(uint4*)&smem[lofsA + bo] = rvA;
        *(uint4*)&smem[lofsB + bo] = rvB;
      }
      __syncthreads();
    }

    const int rg = r0 + wr * 16 + ((lane >> 4) << 2);
    const int cg = l0 + wc * 16 + (lane & 15);
    float rs[4];
#pragma unroll
    for (int j = 0; j < 4; ++j) {
      float pv = pb[rg + j];
      float e0 = __expf((acc[j] + pv) * 0.125f);
      Cg[(size_t)(rg + j) * 512 + cg] = f2bf(e0);
      rs[j] = e0;
    }
#pragma unroll
    for (int off = 1; off < 16; off <<= 1) {
#pragma unroll
      for (int j = 0; j < 4; ++j) rs[j] += __shfl_xor(rs[j], off, 64);
    }
    if ((lane & 15) == 0) {
      int slot = (l0 >> 4) + wc;
#pragma unroll
      for (int j = 0; j < 4; ++j) sp[(unsigned)(rg + j) * 32 + slot] = rs[j];
    }
    __syncthreads();
    if (tid == 0) {
      __threadfence();
      __hip_atomic_store(
          &eflag[((unsigned)(b * 8 + (r0 >> 5)) * 16 + (unsigned)(l0 >> 5)) *
                 16],
          MAGIC, __ATOMIC_RELEASE, __HIP_MEMORY_SCOPE_AGENT);
    }
  } else if (bid < 768) {
    // ---------------- transpose producer (R12 verbatim body)
    int t = bid - 512;
    int b = t >> 6, rem = t & 63;
    int l0 = (rem >> 3) * 64, j0 = (rem & 7) * 64;
    u16(*ts)[65] = (u16(*)[65])smem;
#pragma unroll
    for (int i = 0; i < 4; ++i) {
      int idx = tid + i * 256;
      int row = idx >> 4, c4 = (idx & 15) * 4;
      uint2 u = *(const uint2*)&hb[(size_t)(b * Ln + l0 + row) * EMBn + j0 + c4];
      ts[row][c4] = (u16)(u.x & 0xffffu);
      ts[row][c4 + 1] = (u16)(u.x >> 16);
      ts[row][c4 + 2] = (u16)(u.y & 0xffffu);
      ts[row][c4 + 3] = (u16)(u.y >> 16);
    }
    __syncthreads();
#pragma unroll
    for (int i = 0; i < 4; ++i) {
      int idx = tid + i * 256;
      int jr = idx >> 4, lc4 = (idx & 15) * 4;
      unsigned lo = (unsigned)ts[lc4][jr] | ((unsigned)ts[lc4 + 1][jr] << 16);
      unsigned hi = (unsigned)ts[lc4 + 2][jr] | ((unsigned)ts[lc4 + 3][jr] << 16);
      uint2 u;
      u.x = lo;
      u.y = hi;
      *(uint2*)&htb[(size_t)(b * EMBn + j0 + jr) * Ln + l0 + lc4] = u;
    }
    __syncthreads();
    if (tid == 0) {
      __threadfence();
      __hip_atomic_store(
          &tflag[((unsigned)(b * 8 + (l0 >> 6)) * 8 + (unsigned)(j0 >> 6)) *
                 16],
          MAGIC, __ATOMIC_RELEASE, __HIP_MEMORY_SCOPE_AGENT);
    }
  } else {
    // ---------------- gmat consumer
    int t = bid - 768;
    int b = t >> 7, rem = t & 127;
    int r0 = (rem >> 4) * 32, j0 = (rem & 15) * 32;
    if (tid < 16) {
      unsigned* f =
          &eflag[((unsigned)(b * 8 + (r0 >> 5)) * 16 + (unsigned)tid) * 16];
      while (__hip_atomic_load(f, __ATOMIC_ACQUIRE,
                               __HIP_MEMORY_SCOPE_AGENT) != MAGIC)
        __builtin_amdgcn_s_sleep(2);
    } else if (tid < 24) {
      unsigned* f =
          &tflag[((unsigned)(b * 8 + (tid - 16)) * 8 + (unsigned)(j0 >> 6)) *
                 16];
      while (__hip_atomic_load(f, __ATOMIC_ACQUIRE,
                               __HIP_MEMORY_SCOPE_AGENT) != MAGIC)
        __builtin_amdgcn_s_sleep(2);
    }
    __syncthreads();

    const u16* Ag = Eb + (size_t)b * Rn * Ln;
    const u16* Bg = htb + (size_t)b * EMBn * Ln;
    {
      int rl = tid >> 3, seg = tid & 7;
      const float* sp = spart + ((size_t)b * Rn + r0 + rl) * 32 + seg * 4;
      float4 p4 = *(const float4*)sp;
      float s = p4.x + p4.y + p4.z + p4.w;
      s += __shfl_xor(s, 1, 64);
      s += __shfl_xor(s, 2, 64);
      s += __shfl_xor(s, 4, 64);
      if (seg == 0) sInvS[rl] = 1.0f / s;
    }

    const int wave = tid >> 6, lane = tid & 63;
    const int srow = tid >> 3, sblk = tid & 7;
    const u16* gsrcA = Ag + (size_t)(r0 + srow) * 512 + sblk * 8;
    const u16* gsrcB = Bg + (size_t)(j0 + srow) * 512 + sblk * 8;
    const unsigned lswz = (unsigned)(((sblk * 16) ^ ((srow & 7) << 4)) >> 1);
    const unsigned lofsA = (unsigned)(srow * 64) + lswz;
    const unsigned lofsB = 4096u + (unsigned)(srow * 64) + lswz;

    uint4 rvA = *(const uint4*)gsrcA;
    uint4 rvB = *(const uint4*)gsrcB;
    *(uint4*)&smem[lofsA] = rvA;
    *(uint4*)&smem[lofsB] = rvB;
    __syncthreads();

    f32x4 acc = {0.f, 0.f, 0.f, 0.f};
    const int wr = wave >> 1, wc = wave & 1;
    const int ra = wr * 16 + (lane & 15);
    const int nb = wc * 16 + (lane & 15);
    const unsigned asw = (unsigned)((ra & 7) << 4);
    const unsigned bsw = (unsigned)((nb & 7) << 4);
    const unsigned kg = (unsigned)((lane >> 4) * 16);

#pragma unroll
    for (int c = 0; c < 8; ++c) {
      const int cur = c & 1;
      if (c < 7) {
        rvA = *(const uint4*)(gsrcA + (c + 1) * 64);
        rvB = *(const uint4*)(gsrcB + (c + 1) * 64);
      }
      const char* Ab = (const char*)(smem + cur * 2048);
      const char* Bb = (const char*)(smem + 4096 + cur * 2048);
#pragma unroll
      for (int ks = 0; ks < 2; ++ks) {
        unsigned kb = ks * 64 + kg;
        bf16x8 a = *(const bf16x8*)(Ab + ra * 128 + (kb ^ asw));
        bf16x8 b0 = *(const bf16x8*)(Bb + nb * 128 + (kb ^ bsw));
        acc = __builtin_amdgcn_mfma_f32_16x16x32_bf16(a, b0, acc, 0, 0, 0);
      }
      if (c < 7) {
        unsigned bo = (unsigned)((cur ^ 1) * 2048);
        *(uint4*)&smem[lofsA + bo] = rvA;
        *(uint4*)&smem[lofsB + bo] = rvB;
      }
      __syncthreads();
    }

    const int lrw = wr * 16 + ((lane >> 4) << 2);
    const int rg = r0 + lrw;
    const int cg = j0 + wc * 16 + (lane & 15);
#pragma unroll
    for (int j = 0; j < 4; ++j) {
      Gb[((size_t)b * Rn + rg + j) * 512 + cg] = f2bf(acc[j] * sInvS[lrw + j]);
    }
  }
}

// ---------------------------------------------------------------------------
// K3: out[b,(m,h),s] = dot(v[m,h*64+s,:], G[b,r,:]) + vb[m,h*64+s]
// grid 2048; G bf16 pre-normalized.  (R12 verbatim)
// ---------------------------------------------------------------------------
__global__ __launch_bounds__(256) void out_kernel(
    const float* __restrict__ v, const float* __restrict__ vb,
    const u16* __restrict__ Gb, float* __restrict__ out) {
  int bid = blockIdx.x;
  int sc = bid & 7, hh = (bid >> 3) & 7, m = bid >> 6;
  int r = m * Hn + hh;
  __shared__ float Gs[Bn][EMBn];
  int tid = threadIdx.x;
  {
    int bb = tid >> 6, e8 = (tid & 63) * 8;
    uint4 u = *(const uint4*)&Gb[((size_t)bb * Rn + r) * EMBn + e8];
    Gs[bb][e8 + 0] = bf2f(u.x & 0xffffu);
    Gs[bb][e8 + 1] = bf2f(u.x >> 16);
    Gs[bb][e8 + 2] = bf2f(u.y & 0xffffu);
    Gs[bb][e8 + 3] = bf2f(u.y >> 16);
    Gs[bb][e8 + 4] = bf2f(u.z & 0xffffu);
    Gs[bb][e8 + 5] = bf2f(u.z >> 16);
    Gs[bb][e8 + 6] = bf2f(u.w & 0xffffu);
    Gs[bb][e8 + 7] = bf2f(u.w >> 16);
  }
  __syncthreads();
  int wid = tid >> 6, lane = tid & 63;
  const float* vbase =
      v + ((size_t)m * EMBn + hh * HSn + sc * 8 + wid * 2) * EMBn + lane * 8;
  float4 va[4];
#pragma unroll
  for (int i = 0; i < 2; ++i) {
    va[2 * i] = *(const float4*)(vbase + (size_t)i * EMBn);
    va[2 * i + 1] = *(const float4*)(vbase + (size_t)i * EMBn + 4);
  }
#pragma unroll
  for (int i = 0; i < 2; ++i) {
    int rr = sc * 8 + wid * 2 + i;
    float acc[Bn];
#pragma unroll
    for (int bb = 0; bb < Bn; ++bb) {
      const float* gp = &Gs[bb][lane * 8];
      float4 g0 = *(const float4*)gp;
      float4 g1 = *(const float4*)(gp + 4);
      acc[bb] = va[2 * i].x * g0.x + va[2 * i].y * g0.y +
                va[2 * i].z * g0.z + va[2 * i].w * g0.w +
                va[2 * i + 1].x * g1.x + va[2 * i + 1].y * g1.y +
                va[2 * i + 1].z * g1.z + va[2 * i + 1].w * g1.w;
    }
#pragma unroll
    for (int off = 1; off < 64; off <<= 1) {
#pragma unroll
      for (int bb = 0; bb < Bn; ++bb) acc[bb] += __shfl_xor(acc[bb], off, 64);
    }
    if (lane == 0) {
      float vbv = vb[(size_t)m * EMBn + hh * HSn + rr];
#pragma unroll
      for (int bb = 0; bb < Bn; ++bb) {
        out[(((size_t)bb * Hn + hh) * Mn + m) * HSn + rr] = acc[bb] + vbv;
      }
    }
  }
}

extern "C" void kernel_launch(void* const* d_in, const int* in_sizes, int n_in,
                              void* d_out, int out_size, void* d_ws,
                              size_t ws_size, hipStream_t stream) {
  const float* x = (const float*)d_in[0];
  const float* cells = (const float*)d_in[1];
  const float* q_w = (const float*)d_in[2];
  const float* q_b = (const float*)d_in[3];
  const float* v = (const float*)d_in[4];
  const float* vbp = (const float*)d_in[5];
  const float* ln_g = (const float*)d_in[6];
  const float* ln_b = (const float*)d_in[7];
  float* out = (float*)d_out;

  u16* hb = (u16*)d_ws;                              // 2 MB
  u16* htb = hb + (size_t)Bn * Ln * EMBn;            // 2 MB
  u16* Pb = htb + (size_t)Bn * Ln * EMBn;            // 256 KB
  u16* Eb = Pb + (size_t)Rn * EMBn;                  // 1 MB
  u16* Gb = Eb + (size_t)Bn * Rn * Ln;               // 1 MB
  float* pb = (float*)(Gb + (size_t)Bn * Rn * EMBn); // 1 KB
  float* spart = pb + Rn;                            // 128 KB
  unsigned* flg = (unsigned*)(spart + (size_t)Bn * Rn * 32); // 49 KB

  ln_pproj_kernel<<<640, 256, 0, stream>>>(x, ln_g, ln_b, cells, q_w, q_b, hb,
                                           Pb, pb);
  mid_kernel<<<1280, 256, 0, stream>>>(hb, Pb, pb, Eb, spart, htb, Gb, flg);
  out_kernel<<<2048, 256, 0, stream>>>(v, vbp, Gb, out);
}

// Round 14
// 30.325 us; speedup vs baseline: 2.6557x; 2.6557x over previous
//
#include <hip/hip_runtime.h>

typedef unsigned short u16;
typedef float f32x4 __attribute__((ext_vector_type(4)));
typedef short bf16x8 __attribute__((ext_vector_type(8)));

constexpr int Bn = 4, Ln = 512, Mn = 32, EMBn = 512, Hn = 8, HSn = 64;
constexpr int Rn = Mn * Hn; // 256

__device__ __forceinline__ float wave_sum(float v) {
#pragma unroll
  for (int off = 1; off < 64; off <<= 1) v += __shfl_xor(v, off, 64);
  return v;
}
__device__ __forceinline__ u16 f2bf(float f) {
  unsigned u = __float_as_uint(f);
  unsigned r = (u + 0x7FFFu + ((u >> 16) & 1u)) >> 16;
  return (u16)r;
}
__device__ __forceinline__ unsigned pack2(float a, float b) {
  return (unsigned)f2bf(a) | ((unsigned)f2bf(b) << 16);
}
__device__ __forceinline__ float bf2f(unsigned us) {
  return __uint_as_float(us << 16);
}

// ---------------------------------------------------------------------------
// K1: blocks [0,128): P = cells*q_w via 32x32 MFMA (K=64), + pb (et==0).
//     blocks [128,640): LayerNorm -> h_bf16.   (R12 verbatim)
// ---------------------------------------------------------------------------
__global__ __launch_bounds__(256) void ln_pproj_kernel(
    const float* __restrict__ x, const float* __restrict__ gam,
    const float* __restrict__ bet, const float* __restrict__ cells,
    const float* __restrict__ q_w, const float* __restrict__ q_b,
    u16* __restrict__ hb, u16* __restrict__ Pb, float* __restrict__ pb) {
  __shared__ __align__(16) char PSM[8192];
  int bid = blockIdx.x, tid = threadIdx.x;
  if (bid < 128) {
    int hh = bid >> 4, et = bid & 15;
    int e0 = et * 32;
    const int lane = tid & 63;
    {
      int row = tid >> 3, sc8 = (tid & 7) * 8;
      const float* src = cells + (size_t)(row * Hn + hh) * HSn + sc8;
      float4 c0 = *(const float4*)src;
      float4 c1 = *(const float4*)(src + 4);
      uint4 st;
      st.x = pack2(c0.x, c0.y);
      st.y = pack2(c0.z, c0.w);
      st.z = pack2(c1.x, c1.y);
      st.w = pack2(c1.z, c1.w);
      *(uint4*)(PSM + row * 128 + (((unsigned)(sc8 * 2)) ^ ((row & 7) << 4))) =
          st;
    }
    {
      int srow = tid >> 2, eq = (tid & 3) * 8;
      const float* src = q_w + (size_t)(hh * HSn + srow) * EMBn + e0 + eq;
      float4 q0 = *(const float4*)src;
      float4 q1 = *(const float4*)(src + 4);
      u16 qv[8];
      qv[0] = f2bf(q0.x); qv[1] = f2bf(q0.y);
      qv[2] = f2bf(q0.z); qv[3] = f2bf(q0.w);
      qv[4] = f2bf(q1.x); qv[5] = f2bf(q1.y);
      qv[6] = f2bf(q1.z); qv[7] = f2bf(q1.w);
#pragma unroll
      for (int k = 0; k < 8; ++k) {
        int e = eq + k;
        unsigned swz =
            (((unsigned)(e & 7)) << 4) ^ (((unsigned)((e >> 3) & 3)) << 5);
        *(u16*)(PSM + 4096 + e * 128 + (((unsigned)(srow * 2)) ^ swz)) = qv[k];
      }
    }
    __syncthreads();
    const int wave = tid >> 6;
    const int wr = wave >> 1, wc = wave & 1;
    const int n = lane & 15;
    const int ra = wr * 16 + n;
    const int eb = wc * 16 + n;
    const unsigned asw = (unsigned)((ra & 7) << 4);
    const unsigned bsw =
        (((unsigned)(eb & 7)) << 4) ^ (((unsigned)((eb >> 3) & 3)) << 5);
    const unsigned kg = (unsigned)((lane >> 4) * 16);
    f32x4 acc = {0.f, 0.f, 0.f, 0.f};
#pragma unroll
    for (int kk = 0; kk < 2; ++kk) {
      unsigned kb = kk * 64 + kg;
      bf16x8 a = *(const bf16x8*)(PSM + ra * 128 + (kb ^ asw));
      bf16x8 bv = *(const bf16x8*)(PSM + 4096 + eb * 128 + (kb ^ bsw));
      acc = __builtin_amdgcn_mfma_f32_16x16x32_bf16(a, bv, acc, 0, 0, 0);
    }
    const int m0 = wr * 16 + ((lane >> 4) << 2);
    const int eg = e0 + wc * 16 + n;
#pragma unroll
    for (int j = 0; j < 4; ++j) {
      Pb[(size_t)((m0 + j) * Hn + hh) * EMBn + eg] = f2bf(acc[j]);
    }
    if (et == 0) {
      int m = tid >> 3, sg = tid & 7;
      const float* cp = cells + (size_t)(m * Hn + hh) * HSn + sg * 8;
      const float* qp = q_b + hh * HSn + sg * 8;
      float p = 0.f;
#pragma unroll
      for (int k = 0; k < 8; ++k) p += cp[k] * qp[k];
      p += __shfl_xor(p, 1, 64);
      p += __shfl_xor(p, 2, 64);
      p += __shfl_xor(p, 4, 64);
      if (sg == 0) pb[m * Hn + hh] = p;
    }
  } else {
    int row = (bid - 128) * 4 + (tid >> 6), lane = tid & 63;
    const float* xr = x + (size_t)row * EMBn + lane * 8;
    float4 a0 = *(const float4*)xr;
    float4 a1 = *(const float4*)(xr + 4);
    float s = a0.x + a0.y + a0.z + a0.w + a1.x + a1.y + a1.z + a1.w;
    float ss = a0.x * a0.x + a0.y * a0.y + a0.z * a0.z + a0.w * a0.w +
               a1.x * a1.x + a1.y * a1.y + a1.z * a1.z + a1.w * a1.w;
    s = wave_sum(s);
    ss = wave_sum(ss);
    float mu = s * (1.0f / EMBn);
    float var = ss * (1.0f / EMBn) - mu * mu;
    float rstd = rsqrtf(var + 1e-5f);
    const float* gp = gam + lane * 8;
    const float* bp = bet + lane * 8;
    float4 g0 = *(const float4*)gp, g1 = *(const float4*)(gp + 4);
    float4 b0 = *(const float4*)bp, b1 = *(const float4*)(bp + 4);
    float4 o0, o1;
    o0.x = (a0.x - mu) * rstd * g0.x + b0.x;
    o0.y = (a0.y - mu) * rstd * g0.y + b0.y;
    o0.z = (a0.z - mu) * rstd * g0.z + b0.z;
    o0.w = (a0.w - mu) * rstd * g0.w + b0.w;
    o1.x = (a1.x - mu) * rstd * g1.x + b1.x;
    o1.y = (a1.y - mu) * rstd * g1.y + b1.y;
    o1.z = (a1.z - mu) * rstd * g1.z + b1.z;
    o1.w = (a1.w - mu) * rstd * g1.w + b1.w;
    uint4 st;
    st.x = pack2(o0.x, o0.y);
    st.y = pack2(o0.z, o0.w);
    st.z = pack2(o1.x, o1.y);
    st.w = pack2(o1.z, o1.w);
    *(uint4*)&hb[(size_t)row * EMBn + lane * 8] = st;
  }
}

// ---------------------------------------------------------------------------
// 32x32 MFMA GEMM core, FULL-K register prefetch: all 16 global loads issued
// upfront (latency paid once), LDS double-buffer consumed from registers.
// MODE 0: C f32-normalized->bf16 via sInvS. MODE 1: exp epilogue + spart.
// ---------------------------------------------------------------------------
template <int MODE>
__device__ __forceinline__ void gemm_core32(const u16* __restrict__ Ag,
                                            const u16* __restrict__ Bg,
                                            u16* __restrict__ Cg,
                                            const float* __restrict__ pbv,
                                            float* __restrict__ spart,
                                            const float* __restrict__ sInvS,
                                            int r0, int n0, int tid,
                                            u16* smem) {
  const int wave = tid >> 6, lane = tid & 63;
  const int srow = tid >> 3, sblk = tid & 7;
  const u16* gsrcA = Ag + (size_t)(r0 + srow) * 512 + sblk * 8;
  const u16* gsrcB = Bg + (size_t)(n0 + srow) * 512 + sblk * 8;
  const unsigned lswz = (unsigned)(((sblk * 16) ^ ((srow & 7) << 4)) >> 1);
  const unsigned lofsA = (unsigned)(srow * 64) + lswz;
  const unsigned lofsB = 4096u + (unsigned)(srow * 64) + lswz;

  // full-K upfront loads (16 outstanding, one latency exposure)
  uint4 pA0 = *(const uint4*)(gsrcA + 0 * 64);
  uint4 pB0 = *(const uint4*)(gsrcB + 0 * 64);
  uint4 pA1 = *(const uint4*)(gsrcA + 1 * 64);
  uint4 pB1 = *(const uint4*)(gsrcB + 1 * 64);
  uint4 pA2 = *(const uint4*)(gsrcA + 2 * 64);
  uint4 pB2 = *(const uint4*)(gsrcB + 2 * 64);
  uint4 pA3 = *(const uint4*)(gsrcA + 3 * 64);
  uint4 pB3 = *(const uint4*)(gsrcB + 3 * 64);
  uint4 pA4 = *(const uint4*)(gsrcA + 4 * 64);
  uint4 pB4 = *(const uint4*)(gsrcB + 4 * 64);
  uint4 pA5 = *(const uint4*)(gsrcA + 5 * 64);
  uint4 pB5 = *(const uint4*)(gsrcB + 5 * 64);
  uint4 pA6 = *(const uint4*)(gsrcA + 6 * 64);
  uint4 pB6 = *(const uint4*)(gsrcB + 6 * 64);
  uint4 pA7 = *(const uint4*)(gsrcA + 7 * 64);
  uint4 pB7 = *(const uint4*)(gsrcB + 7 * 64);

  *(uint4*)&smem[lofsA] = pA0;
  *(uint4*)&smem[lofsB] = pB0;
  __syncthreads();

  f32x4 acc = {0.f, 0.f, 0.f, 0.f};
  const int wr = wave >> 1, wc = wave & 1;
  const int ra = wr * 16 + (lane & 15);
  const int nb = wc * 16 + (lane & 15);
  const unsigned asw = (unsigned)((ra & 7) << 4);
  const unsigned bsw = (unsigned)((nb & 7) << 4);
  const unsigned kg = (unsigned)((lane >> 4) * 16);

#pragma unroll
  for (int c = 0; c < 8; ++c) {
    const int cur = c & 1;
    const char* Ab = (const char*)(smem + cur * 2048);
    const char* Bb = (const char*)(smem + 4096 + cur * 2048);
#pragma unroll
    for (int ks = 0; ks < 2; ++ks) {
      unsigned kb = ks * 64 + kg;
      bf16x8 a = *(const bf16x8*)(Ab + ra * 128 + (kb ^ asw));
      bf16x8 b0 = *(const bf16x8*)(Bb + nb * 128 + (kb ^ bsw));
      acc = __builtin_amdgcn_mfma_f32_16x16x32_bf16(a, b0, acc, 0, 0, 0);
    }
    if (c < 7) {
      unsigned bo = (unsigned)((cur ^ 1) * 2048);
      uint4 wA, wB;
      switch (c) {
        case 0: wA = pA1; wB = pB1; break;
        case 1: wA = pA2; wB = pB2; break;
        case 2: wA = pA3; wB = pB3; break;
        case 3: wA = pA4; wB = pB4; break;
        case 4: wA = pA5; wB = pB5; break;
        case 5: wA = pA6; wB = pB6; break;
        default: wA = pA7; wB = pB7; break;
      }
      *(uint4*)&smem[lofsA + bo] = wA;
      *(uint4*)&smem[lofsB + bo] = wB;
    }
    __syncthreads();
  }

  const int lrw = wr * 16 + ((lane >> 4) << 2);
  const int rg = r0 + lrw;
  const int cg = n0 + wc * 16 + (lane & 15);
  if (MODE == 0) {
#pragma unroll
    for (int j = 0; j < 4; ++j) {
      Cg[(size_t)(rg + j) * 512 + cg] = f2bf(acc[j] * sInvS[lrw + j]);
    }
  } else {
    float rs[4];
#pragma unroll
    for (int j = 0; j < 4; ++j) {
      float pv = pbv[rg + j];
      float e0 = __expf((acc[j] + pv) * 0.125f);
      Cg[(size_t)(rg + j) * 512 + cg] = f2bf(e0);
      rs[j] = e0;
    }
#pragma unroll
    for (int off = 1; off < 16; off <<= 1) {
#pragma unroll
      for (int j = 0; j < 4; ++j) rs[j] += __shfl_xor(rs[j], off, 64);
    }
    if ((lane & 15) == 0) {
      int slot = (n0 >> 4) + wc;
#pragma unroll
      for (int j = 0; j < 4; ++j) spart[(unsigned)(rg + j) * 32 + slot] = rs[j];
    }
  }
}

// ---------------------------------------------------------------------------
// K2: blocks [0,512): E = exp((P.h^T+pb)/8) bf16 + partial sums (32x32)
//     blocks [512,768): transpose h -> htb[b][j][l].
// ---------------------------------------------------------------------------
__global__ __launch_bounds__(256) void escore_trans_kernel(
    const u16* __restrict__ hb, const u16* __restrict__ Pb,
    const float* __restrict__ pb, u16* __restrict__ Eb,
    float* __restrict__ spart, u16* __restrict__ htb) {
  __shared__ u16 smem[8192];
  int bid = blockIdx.x, tid = threadIdx.x;
  if (bid < 512) {
    int b = bid >> 7, rem = bid & 127;
    int r0 = (rem >> 4) * 32, l0 = (rem & 15) * 32;
    gemm_core32<1>(Pb, hb + (size_t)b * Ln * EMBn, Eb + (size_t)b * Rn * Ln,
                   pb, spart + (size_t)b * Rn * 32, nullptr, r0, l0, tid,
                   smem);
  } else {
    int t = bid - 512;
    int b = t >> 6, rem = t & 63;
    int l0 = (rem >> 3) * 64, j0 = (rem & 7) * 64;
    u16(*ts)[65] = (u16(*)[65])smem;
    uint2 ld[4];
#pragma unroll
    for (int i = 0; i < 4; ++i) {
      int idx = tid + i * 256;
      int row = idx >> 4, c4 = (idx & 15) * 4;
      ld[i] = *(const uint2*)&hb[(size_t)(b * Ln + l0 + row) * EMBn + j0 + c4];
    }
#pragma unroll
    for (int i = 0; i < 4; ++i) {
      int idx = tid + i * 256;
      int row = idx >> 4, c4 = (idx & 15) * 4;
      ts[row][c4] = (u16)(ld[i].x & 0xffffu);
      ts[row][c4 + 1] = (u16)(ld[i].x >> 16);
      ts[row][c4 + 2] = (u16)(ld[i].y & 0xffffu);
      ts[row][c4 + 3] = (u16)(ld[i].y >> 16);
    }
    __syncthreads();
#pragma unroll
    for (int i = 0; i < 4; ++i) {
      int idx = tid + i * 256;
      int jr = idx >> 4, lc4 = (idx & 15) * 4;
      unsigned lo = (unsigned)ts[lc4][jr] | ((unsigned)ts[lc4 + 1][jr] << 16);
      unsigned hi = (unsigned)ts[lc4 + 2][jr] | ((unsigned)ts[lc4 + 3][jr] << 16);
      uint2 u;
      u.x = lo;
      u.y = hi;
      *(uint2*)&htb[(size_t)(b * EMBn + j0 + jr) * Ln + l0 + lc4] = u;
    }
  }
}

// ---------------------------------------------------------------------------
// K3: G[b][r][j] = (sum_l E*ht) * sInv[r], bf16 out. 32x32 tiles, 512 blocks.
// ---------------------------------------------------------------------------
__global__ __launch_bounds__(256) void gmat_kernel(
    const u16* __restrict__ Eb, const u16* __restrict__ htb,
    const float* __restrict__ spart, u16* __restrict__ Gb) {
  __shared__ u16 smem[8192];
  __shared__ float sInvS[32];
  int bid = blockIdx.x, tid = threadIdx.x;
  int b = bid >> 7, rem = bid & 127;
  int r0 = (rem >> 4) * 32, j0 = (rem & 15) * 32;
  {
    int rl = tid >> 3, seg = tid & 7;
    const float* sp = spart + ((size_t)b * Rn + r0 + rl) * 32 + seg * 4;
    float4 p4 = *(const float4*)sp;
    float s = p4.x + p4.y + p4.z + p4.w;
    s += __shfl_xor(s, 1, 64);
    s += __shfl_xor(s, 2, 64);
    s += __shfl_xor(s, 4, 64);
    if (seg == 0) sInvS[rl] = 1.0f / s;
  }
  gemm_core32<0>(Eb + (size_t)b * Rn * Ln, htb + (size_t)b * EMBn * Ln,
                 Gb + (size_t)b * Rn * EMBn, nullptr, nullptr, sInvS, r0, j0,
                 tid, smem);
}

// ---------------------------------------------------------------------------
// K4: out[b,(m,h),s] = dot(v[m,h*64+s,:], G[b,r,:]) + vb[m,h*64+s]
// grid 2048; v loads issued BEFORE the Gs staging barrier.
// ---------------------------------------------------------------------------
__global__ __launch_bounds__(256) void out_kernel(
    const float* __restrict__ v, const float* __restrict__ vb,
    const u16* __restrict__ Gb, float* __restrict__ out) {
  int bid = blockIdx.x;
  int sc = bid & 7, hh = (bid >> 3) & 7, m = bid >> 6;
  int r = m * Hn + hh;
  __shared__ float Gs[Bn][EMBn];
  int tid = threadIdx.x;
  int wid = tid >> 6, lane = tid & 63;
  // issue v loads first (independent of Gs)
  const float* vbase =
      v + ((size_t)m * EMBn + hh * HSn + sc * 8 + wid * 2) * EMBn + lane * 8;
  float4 va[4];
#pragma unroll
  for (int i = 0; i < 2; ++i) {
    va[2 * i] = *(const float4*)(vbase + (size_t)i * EMBn);
    va[2 * i + 1] = *(const float4*)(vbase + (size_t)i * EMBn + 4);
  }
  {
    int bb = tid >> 6, e8 = (tid & 63) * 8;
    uint4 u = *(const uint4*)&Gb[((size_t)bb * Rn + r) * EMBn + e8];
    Gs[bb][e8 + 0] = bf2f(u.x & 0xffffu);
    Gs[bb][e8 + 1] = bf2f(u.x >> 16);
    Gs[bb][e8 + 2] = bf2f(u.y & 0xffffu);
    Gs[bb][e8 + 3] = bf2f(u.y >> 16);
    Gs[bb][e8 + 4] = bf2f(u.z & 0xffffu);
    Gs[bb][e8 + 5] = bf2f(u.z >> 16);
    Gs[bb][e8 + 6] = bf2f(u.w & 0xffffu);
    Gs[bb][e8 + 7] = bf2f(u.w >> 16);
  }
  __syncthreads();
#pragma unroll
  for (int i = 0; i < 2; ++i) {
    int rr = sc * 8 + wid * 2 + i;
    float acc[Bn];
#pragma unroll
    for (int bb = 0; bb < Bn; ++bb) {
      const float* gp = &Gs[bb][lane * 8];
      float4 g0 = *(const float4*)gp;
      float4 g1 = *(const float4*)(gp + 4);
      acc[bb] = va[2 * i].x * g0.x + va[2 * i].y * g0.y +
                va[2 * i].z * g0.z + va[2 * i].w * g0.w +
                va[2 * i + 1].x * g1.x + va[2 * i + 1].y * g1.y +
                va[2 * i + 1].z * g1.z + va[2 * i + 1].w * g1.w;
    }
#pragma unroll
    for (int off = 1; off < 64; off <<= 1) {
#pragma unroll
      for (int bb = 0; bb < Bn; ++bb) acc[bb] += __shfl_xor(acc[bb], off, 64);
    }
    if (lane == 0) {
      float vbv = vb[(size_t)m * EMBn + hh * HSn + rr];
#pragma unroll
      for (int bb = 0; bb < Bn; ++bb) {
        out[(((size_t)bb * Hn + hh) * Mn + m) * HSn + rr] = acc[bb] + vbv;
      }
    }
  }
}

extern "C" void kernel_launch(void* const* d_in, const int* in_sizes, int n_in,
                              void* d_out, int out_size, void* d_ws,
                              size_t ws_size, hipStream_t stream) {
  const float* x = (const float*)d_in[0];
  const float* cells = (const float*)d_in[1];
  const float* q_w = (const float*)d_in[2];
  const float* q_b = (const float*)d_in[3];
  const float* v = (const float*)d_in[4];
  const float* vbp = (const float*)d_in[5];
  const float* ln_g = (const float*)d_in[6];
  const float* ln_b = (const float*)d_in[7];
  float* out = (float*)d_out;

  u16* hb = (u16*)d_ws;                              // 2 MB
  u16* htb = hb + (size_t)Bn * Ln * EMBn;            // 2 MB
  u16* Pb = htb + (size_t)Bn * Ln * EMBn;            // 256 KB
  u16* Eb = Pb + (size_t)Rn * EMBn;                  // 1 MB
  u16* Gb = Eb + (size_t)Bn * Rn * Ln;               // 1 MB
  float* pb = (float*)(Gb + (size_t)Bn * Rn * EMBn); // 1 KB
  float* spart = pb + Rn;                            // 128 KB

  ln_pproj_kernel<<<640, 256, 0, stream>>>(x, ln_g, ln_b, cells, q_w, q_b, hb,
                                           Pb, pb);
  escore_trans_kernel<<<768, 256, 0, stream>>>(hb, Pb, pb, Eb, spart, htb);
  gmat_kernel<<<512, 256, 0, stream>>>(Eb, htb, spart, Gb);
  out_kernel<<<2048, 256, 0, stream>>>(v, vbp, Gb, out);
}